// Round 19
// baseline (211.041 us; speedup 1.0000x reference)
//
#include <hip/hip_runtime.h>
#include <hip/hip_bf16.h>

#define B    64
#define T    4096
#define V    64
#define NQ   64      // NGRAN * NGLIMPSE
#define NHID 2048
#define KDIM 4096    // V * NQ
#define FAN  4097    // KDIM + 1 (l_t column)

#define NBLK   1024  // persistent grid: 4 blocks/CU x 256 CUs (co-resident)
#define NT     16    // h rows per tile
#define SPLITS 32    // k-splits
#define KC     128   // k per split (KDIM/SPLITS)
#define TILES  4     // h-tiles per block (same k-slice -> A staged once)

typedef __attribute__((ext_vector_type(8))) short bf16x8;
typedef __attribute__((ext_vector_type(4))) float f32x4;

static __device__ __forceinline__ short f2bf(float x) {
    union { float f; unsigned u; } c; c.f = x;
    unsigned r = c.u + 0x7fff + ((c.u >> 16) & 1);   // RNE
    return (short)(r >> 16);
}

static __device__ __forceinline__ void load_lds16(const void* g, void* l) {
    __builtin_amdgcn_global_load_lds(
        (const __attribute__((address_space(1))) void*)g,
        (__attribute__((address_space(3))) void*)l, 16, 0, 0);
}

static __device__ __forceinline__ unsigned cvt_pk(float lo, float hi) {
    unsigned r;
    asm volatile("v_cvt_pk_bf16_f32 %0, %1, %2" : "=v"(r) : "v"(lo), "v"(hi));
    return r;
}

// ---------------------------------------------------------------------------
// Fused persistent kernel (ONE dispatch; W stream starts at t=0 and overlaps
// the glimpse latency chain). Per block (bid): s = bid&31 (k-slice),
// ht0 = bid>>5.
//   1. issue tile-0 W gload_lds (fire-and-forget)
//   2. glimpse: 4 (b,q) pairs (one per wave, lane = v) -> g_bf, out2
//   3. zero out[bid*128 .. +128)
//   4. device-scope arrive; spin until all NBLK arrived (co-resident by
//      construction: 24KB LDS, launch_bounds(256,4), grid = 4 x 256 CUs)
//   5. stage A = g_bf[0..64)[s*128..+128) once (gload_lds + XOR swizzle)
//      [R18 bug fixed: wave-chunk m = 4 rows x 128 cols = 512 shorts ->
//       dest alds + m*512, NOT m*1024 (which clobbered wlds -> NaN)]
//   6. 4 tiles: {vmcnt+barrier, MFMA, stage next W, atomic tail}
// ---------------------------------------------------------------------------
__global__ __launch_bounds__(256, 4) void fused_kernel(
    const float* __restrict__ vals, const float* __restrict__ time_,
    const int* __restrict__ masks, const float* __restrict__ l_t,
    const float* __restrict__ W, const float* __restrict__ bias,
    unsigned short* __restrict__ g_bf, unsigned* __restrict__ cnt,
    float* __restrict__ out2, float* __restrict__ out)
{
    __shared__ unsigned short alds[B * KC];     // 16 KB
    __shared__ float wlds[NT * KC];             // 8 KB
    const int tid  = threadIdx.x;
    const int l    = tid & 63;
    const int w    = tid >> 6;
    const int l15  = l & 15;
    const int lk   = l >> 4;
    const int bid  = blockIdx.x;
    const int s    = bid & (SPLITS - 1);
    const int ht0  = bid >> 5;
    const int kbase = s * KC;

    // ---- 1. prefetch tile-0 W (rows ht0*16..+16, cols kbase..+128 fp32) ----
    {
        const int hb = ht0 * NT;
        #pragma unroll
        for (int i = 0; i < 2; ++i) {
            const int m = w * 2 + i;            // 0..7: rows 2m, 2m+1
            const int r = 2 * m + (l >> 5);
            const int c = (l & 31) ^ (r & 7);   // 16B fp32 chunk, inv-swizzled
            load_lds16(W + (size_t)(hb + r) * FAN + kbase + c * 4,
                       wlds + m * 256);         // 256 floats per m-chunk
        }
    }

    // ---- 2. glimpse: pair = bid*4 + w ----
    {
        const int pair = bid * 4 + w;
        const int b = pair >> 6;
        const int q = pair & 63;
        const int v = l;

        const float* t = time_ + (size_t)b * T;
        const float tmax = t[T - 1];            // times sorted ascending

        const int   j = q & 31;
        const float sc = (q < 32) ? 1.0f : 5.0f;
        const float a = 0.5f * 0.1f * sc;       // gwidth*scale/2
        const float step = (2.0f * a) / 31.0f;
        float lin = (j == 31) ? a : (-a + step * (float)j);
        const float r = (lin + l_t[b]) * tmax;

        int lo = 0, hi = T;                     // first index with t[] > r
        while (lo < hi) {
            int mid = (lo + hi) >> 1;
            if (t[mid] > r) hi = mid; else lo = mid + 1;
        }
        const int p = lo;

        const int*   m  = masks + (size_t)b * T * V + v;
        const float* vv = vals  + (size_t)b * T * V + v;

        int i0 = -1;
        for (int i = p - 1; i >= 0; --i) {
            if (m[(size_t)i * V] != 0) { i0 = i; break; }
        }
        int i1 = -1;
        for (int i = p; i < T; ++i) {
            if (m[(size_t)i * V] != 0) { i1 = i; break; }
        }

        float y;
        if (i0 < 0 && i1 < 0) {
            y = 0.0f;
        } else if (i0 < 0) {
            y = vv[(size_t)i1 * V];
        } else if (i1 < 0) {
            y = vv[(size_t)i0 * V];
        } else {
            float t0 = t[i0], t1 = t[i1];
            float v0 = vv[(size_t)i0 * V], v1 = vv[(size_t)i1 * V];
            float den = (t1 > t0) ? (t1 - t0) : 1.0f;
            float ww = (r - t0) / den;
            ww = fminf(fmaxf(ww, 0.0f), 1.0f);
            y = v0 + ww * (v1 - v0);
        }

        const int k = v * NQ + q;
        g_bf[(size_t)b * KDIM + k] = (unsigned short)f2bf(y);
        if (k == KDIM / 2) out2[b] = y;         // g[:, 2048], fp32
    }

    // ---- 3. zero this block's out slice (tails atomicAdd after barrier) ----
    if (tid < 128) out[(size_t)bid * 128 + tid] = 0.0f;

    // ---- 4. device-scope arrive + spin (all blocks co-resident) ----
    __syncthreads();
    if (tid == 0) {
        __threadfence();
        atomicAdd(cnt, 1u);
        while (__hip_atomic_load(cnt, __ATOMIC_ACQUIRE,
                                 __HIP_MEMORY_SCOPE_AGENT) < NBLK) {
            __builtin_amdgcn_s_sleep(2);
        }
    }
    __syncthreads();

    // ---- 5. stage A once: g_bf[0..64)[kbase..+128) (shared by 4 tiles) ----
    #pragma unroll
    for (int i = 0; i < 4; ++i) {
        const int m = w * 4 + i;                // 0..15: rows 4m..4m+3
        const int r = 4 * m + (l >> 4);
        const int c = (l & 15) ^ (r & 7);       // 16B bf16 chunk, inv-swizzled
        load_lds16(g_bf + (size_t)r * KDIM + kbase + c * 8,
                   alds + m * 512);             // 512 shorts per m-chunk (FIX)
    }

    // ---- 6. tiles ----
    const int ra = w * 16 + l15;                // A row (b)
    const int rb = l15;                         // W row (h offset)

    #pragma unroll
    for (int j = 0; j < TILES; ++j) {
        const int hb = (ht0 + 32 * j) * NT;

        asm volatile("s_waitcnt vmcnt(0)" ::: "memory");
        __syncthreads();

        f32x4 acc = (f32x4){0.f, 0.f, 0.f, 0.f};
        #pragma unroll
        for (int ks = 0; ks < KC / 32; ++ks) {
            const int ca = ks * 4 + lk;         // A 16B-chunk index
            const bf16x8 afrag =
                *(const bf16x8*)(alds + ra * KC + ((ca ^ (ra & 7)) << 3));

            const int cb = ks * 8 + lk * 2;     // W 16B-chunk (4 fp32) index
            const float4 f0 = *(const float4*)(wlds + rb * KC + (((cb    ) ^ (rb & 7)) << 2));
            const float4 f1 = *(const float4*)(wlds + rb * KC + (((cb + 1) ^ (rb & 7)) << 2));
            union { unsigned u[4]; bf16x8 v; } bb;
            bb.u[0] = cvt_pk(f0.x, f0.y);
            bb.u[1] = cvt_pk(f0.z, f0.w);
            bb.u[2] = cvt_pk(f1.x, f1.y);
            bb.u[3] = cvt_pk(f1.z, f1.w);

            acc = __builtin_amdgcn_mfma_f32_16x16x32_bf16(afrag, bb.v, acc, 0, 0, 0);
        }

        __syncthreads();                        // all waves done reading wlds

        // stage NEXT tile's W while this tile's tail atomics drain
        if (j + 1 < TILES) {
            const int hbn = (ht0 + 32 * (j + 1)) * NT;
            #pragma unroll
            for (int i = 0; i < 2; ++i) {
                const int m = w * 2 + i;
                const int r = 2 * m + (l >> 5);
                const int c = (l & 31) ^ (r & 7);
                load_lds16(W + (size_t)(hbn + r) * FAN + kbase + c * 4,
                           wlds + m * 256);
            }
        }

        // tail: C/D layout col = l15 (h), row = lk*4 + reg (b in 16-tile)
        const int h = hb + l15;
        #pragma unroll
        for (int rr = 0; rr < 4; ++rr) {
            const int b = w * 16 + lk * 4 + rr;
            float v = acc[rr];
            if (s == 0)
                v += bias[h] + l_t[b] * W[(size_t)h * FAN + KDIM];
            atomicAdd(&out[(size_t)b * NHID + h], v);
        }
    }
}

extern "C" void kernel_launch(void* const* d_in, const int* in_sizes, int n_in,
                              void* d_out, int out_size, void* d_ws, size_t ws_size,
                              hipStream_t stream) {
    const float* vals  = (const float*)d_in[0];
    const float* time_ = (const float*)d_in[1];
    const int*   masks = (const int*)d_in[2];
    // d_in[3] = lengths (all == T, unused)
    const float* l_t   = (const float*)d_in[4];
    const float* W     = (const float*)d_in[5];
    const float* bias  = (const float*)d_in[6];

    float* out  = (float*)d_out;                 // grep [B, NHID]
    float* out2 = out + (size_t)B * NHID;        // g[:, 2048]  [B]
    unsigned short* g_bf = (unsigned short*)d_ws;           // 512 KB
    unsigned* cnt = (unsigned*)((char*)d_ws + (1 << 20));   // arrival counter

    hipMemsetAsync(cnt, 0, sizeof(unsigned), stream);       // re-zero each call

    fused_kernel<<<NBLK, 256, 0, stream>>>(vals, time_, masks, l_t, W, bias,
                                           g_bf, cnt, out2, out);
}

// Round 20
// 205.581 us; speedup vs baseline: 1.0266x; 1.0266x over previous
//
#include <hip/hip_runtime.h>
#include <hip/hip_bf16.h>

#define B    64
#define T    4096
#define V    64
#define NQ   64      // NGRAN * NGLIMPSE
#define NHID 2048
#define KDIM 4096    // V * NQ
#define FAN  4097    // KDIM + 1 (l_t column)

#define NBLK   1024  // persistent grid: 4 blocks/CU x 256 CUs (co-resident)
#define NT     16    // h rows per tile
#define SPLITS 32    // k-splits
#define KC     128   // k per split (KDIM/SPLITS)
#define TILES  4     // h-tiles per block (same k-slice -> A staged once)

typedef __attribute__((ext_vector_type(8))) short bf16x8;
typedef __attribute__((ext_vector_type(4))) float f32x4;

static __device__ __forceinline__ short f2bf(float x) {
    union { float f; unsigned u; } c; c.f = x;
    unsigned r = c.u + 0x7fff + ((c.u >> 16) & 1);   // RNE
    return (short)(r >> 16);
}

static __device__ __forceinline__ void load_lds16(const void* g, void* l) {
    __builtin_amdgcn_global_load_lds(
        (const __attribute__((address_space(1))) void*)g,
        (__attribute__((address_space(3))) void*)l, 16, 0, 0);
}

static __device__ __forceinline__ unsigned cvt_pk(float lo, float hi) {
    unsigned r;
    asm volatile("v_cvt_pk_bf16_f32 %0, %1, %2" : "=v"(r) : "v"(lo), "v"(hi));
    return r;
}

// ---------------------------------------------------------------------------
// Fused persistent kernel. R19 lesson: vmcnt is IN-ORDER — a prefetch issued
// BEFORE a dependent-load chain forces every consumer wait to drain the
// prefetch first (211us). So: glimpse FIRST (clean vmcnt), W tile-0 prefetch
// issued AFTER the wave's glimpse work, draining under the arrive-spin +
// A-stage. Per block (bid): s = bid&31 (k-slice), ht0 = bid>>5.
//   1. glimpse: 4 (b,q) pairs (one per wave, lane = v) -> g_bf, out2
//   2. issue tile-0 W gload_lds (fire-and-forget, overlaps barrier wait)
//   3. zero out[bid*128 .. +128)
//   4. device-scope arrive; spin until all NBLK arrived (co-resident by
//      construction: 24KB LDS, launch_bounds(256,4), grid = 4 x 256 CUs)
//   5. stage A = g_bf[0..64)[s*128..+128) once (gload_lds + XOR swizzle)
//   6. 4 tiles: {vmcnt+barrier, MFMA, stage next W, atomic tail}
// ---------------------------------------------------------------------------
__global__ __launch_bounds__(256, 4) void fused_kernel(
    const float* __restrict__ vals, const float* __restrict__ time_,
    const int* __restrict__ masks, const float* __restrict__ l_t,
    const float* __restrict__ W, const float* __restrict__ bias,
    unsigned short* __restrict__ g_bf, unsigned* __restrict__ cnt,
    float* __restrict__ out2, float* __restrict__ out)
{
    __shared__ unsigned short alds[B * KC];     // 16 KB
    __shared__ float wlds[NT * KC];             // 8 KB
    const int tid  = threadIdx.x;
    const int l    = tid & 63;
    const int w    = tid >> 6;
    const int l15  = l & 15;
    const int lk   = l >> 4;
    const int bid  = blockIdx.x;
    const int s    = bid & (SPLITS - 1);
    const int ht0  = bid >> 5;
    const int kbase = s * KC;

    // ---- 1. glimpse: pair = bid*4 + w (no prior VMEM in flight!) ----
    {
        const int pair = bid * 4 + w;
        const int b = pair >> 6;
        const int q = pair & 63;
        const int v = l;

        const float* t = time_ + (size_t)b * T;
        const float tmax = t[T - 1];            // times sorted ascending

        const int   j = q & 31;
        const float sc = (q < 32) ? 1.0f : 5.0f;
        const float a = 0.5f * 0.1f * sc;       // gwidth*scale/2
        const float step = (2.0f * a) / 31.0f;
        float lin = (j == 31) ? a : (-a + step * (float)j);
        const float r = (lin + l_t[b]) * tmax;

        int lo = 0, hi = T;                     // first index with t[] > r
        while (lo < hi) {
            int mid = (lo + hi) >> 1;
            if (t[mid] > r) hi = mid; else lo = mid + 1;
        }
        const int p = lo;

        const int*   m  = masks + (size_t)b * T * V + v;
        const float* vv = vals  + (size_t)b * T * V + v;

        int i0 = -1;
        for (int i = p - 1; i >= 0; --i) {
            if (m[(size_t)i * V] != 0) { i0 = i; break; }
        }
        int i1 = -1;
        for (int i = p; i < T; ++i) {
            if (m[(size_t)i * V] != 0) { i1 = i; break; }
        }

        float y;
        if (i0 < 0 && i1 < 0) {
            y = 0.0f;
        } else if (i0 < 0) {
            y = vv[(size_t)i1 * V];
        } else if (i1 < 0) {
            y = vv[(size_t)i0 * V];
        } else {
            float t0 = t[i0], t1 = t[i1];
            float v0 = vv[(size_t)i0 * V], v1 = vv[(size_t)i1 * V];
            float den = (t1 > t0) ? (t1 - t0) : 1.0f;
            float ww = (r - t0) / den;
            ww = fminf(fmaxf(ww, 0.0f), 1.0f);
            y = v0 + ww * (v1 - v0);
        }

        const int k = v * NQ + q;
        g_bf[(size_t)b * KDIM + k] = (unsigned short)f2bf(y);
        if (k == KDIM / 2) out2[b] = y;         // g[:, 2048], fp32
    }

    // ---- 2. NOW prefetch tile-0 W (drains under spin + A-stage) ----
    {
        const int hb = ht0 * NT;
        #pragma unroll
        for (int i = 0; i < 2; ++i) {
            const int m = w * 2 + i;            // 0..7: rows 2m, 2m+1
            const int r = 2 * m + (l >> 5);
            const int c = (l & 31) ^ (r & 7);   // 16B fp32 chunk, inv-swizzled
            load_lds16(W + (size_t)(hb + r) * FAN + kbase + c * 4,
                       wlds + m * 256);         // 256 floats per m-chunk
        }
    }

    // ---- 3. zero this block's out slice (tails atomicAdd after barrier) ----
    if (tid < 128) out[(size_t)bid * 128 + tid] = 0.0f;

    // ---- 4. device-scope arrive + spin (all blocks co-resident) ----
    __syncthreads();
    if (tid == 0) {
        __threadfence();
        atomicAdd(cnt, 1u);
        while (__hip_atomic_load(cnt, __ATOMIC_ACQUIRE,
                                 __HIP_MEMORY_SCOPE_AGENT) < NBLK) {
            __builtin_amdgcn_s_sleep(8);
        }
    }
    __syncthreads();

    // ---- 5. stage A once: g_bf[0..64)[kbase..+128) (shared by 4 tiles) ----
    #pragma unroll
    for (int i = 0; i < 4; ++i) {
        const int m = w * 4 + i;                // 0..15: rows 4m..4m+3
        const int r = 4 * m + (l >> 4);
        const int c = (l & 15) ^ (r & 7);       // 16B bf16 chunk, inv-swizzled
        load_lds16(g_bf + (size_t)r * KDIM + kbase + c * 8,
                   alds + m * 512);             // 512 shorts per m-chunk
    }

    // ---- 6. tiles ----
    const int ra = w * 16 + l15;                // A row (b)
    const int rb = l15;                         // W row (h offset)

    #pragma unroll
    for (int j = 0; j < TILES; ++j) {
        const int hb = (ht0 + 32 * j) * NT;

        asm volatile("s_waitcnt vmcnt(0)" ::: "memory");
        __syncthreads();

        f32x4 acc = (f32x4){0.f, 0.f, 0.f, 0.f};
        #pragma unroll
        for (int ks = 0; ks < KC / 32; ++ks) {
            const int ca = ks * 4 + lk;         // A 16B-chunk index
            const bf16x8 afrag =
                *(const bf16x8*)(alds + ra * KC + ((ca ^ (ra & 7)) << 3));

            const int cb = ks * 8 + lk * 2;     // W 16B-chunk (4 fp32) index
            const float4 f0 = *(const float4*)(wlds + rb * KC + (((cb    ) ^ (rb & 7)) << 2));
            const float4 f1 = *(const float4*)(wlds + rb * KC + (((cb + 1) ^ (rb & 7)) << 2));
            union { unsigned u[4]; bf16x8 v; } bb;
            bb.u[0] = cvt_pk(f0.x, f0.y);
            bb.u[1] = cvt_pk(f0.z, f0.w);
            bb.u[2] = cvt_pk(f1.x, f1.y);
            bb.u[3] = cvt_pk(f1.z, f1.w);

            acc = __builtin_amdgcn_mfma_f32_16x16x32_bf16(afrag, bb.v, acc, 0, 0, 0);
        }

        __syncthreads();                        // all waves done reading wlds

        // stage NEXT tile's W while this tile's tail atomics drain
        if (j + 1 < TILES) {
            const int hbn = (ht0 + 32 * (j + 1)) * NT;
            #pragma unroll
            for (int i = 0; i < 2; ++i) {
                const int m = w * 2 + i;
                const int r = 2 * m + (l >> 5);
                const int c = (l & 31) ^ (r & 7);
                load_lds16(W + (size_t)(hbn + r) * FAN + kbase + c * 4,
                           wlds + m * 256);
            }
        }

        // tail: C/D layout col = l15 (h), row = lk*4 + reg (b in 16-tile)
        const int h = hb + l15;
        #pragma unroll
        for (int rr = 0; rr < 4; ++rr) {
            const int b = w * 16 + lk * 4 + rr;
            float v = acc[rr];
            if (s == 0)
                v += bias[h] + l_t[b] * W[(size_t)h * FAN + KDIM];
            atomicAdd(&out[(size_t)b * NHID + h], v);
        }
    }
}

extern "C" void kernel_launch(void* const* d_in, const int* in_sizes, int n_in,
                              void* d_out, int out_size, void* d_ws, size_t ws_size,
                              hipStream_t stream) {
    const float* vals  = (const float*)d_in[0];
    const float* time_ = (const float*)d_in[1];
    const int*   masks = (const int*)d_in[2];
    // d_in[3] = lengths (all == T, unused)
    const float* l_t   = (const float*)d_in[4];
    const float* W     = (const float*)d_in[5];
    const float* bias  = (const float*)d_in[6];

    float* out  = (float*)d_out;                 // grep [B, NHID]
    float* out2 = out + (size_t)B * NHID;        // g[:, 2048]  [B]
    unsigned short* g_bf = (unsigned short*)d_ws;           // 512 KB
    unsigned* cnt = (unsigned*)((char*)d_ws + (1 << 20));   // arrival counter

    hipMemsetAsync(cnt, 0, sizeof(unsigned), stream);       // re-zero each call

    fused_kernel<<<NBLK, 256, 0, stream>>>(vals, time_, masks, l_t, W, bias,
                                           g_bf, cnt, out2, out);
}

// Round 21
// 167.067 us; speedup vs baseline: 1.2632x; 1.2305x over previous
//
#include <hip/hip_runtime.h>
#include <hip/hip_bf16.h>

#define B    64
#define T    4096
#define V    64
#define NQ   64      // NGRAN * NGLIMPSE
#define NHID 2048
#define KDIM 4096    // V * NQ
#define FAN  4097    // KDIM + 1 (l_t column)

#define NBLK   1024  // persistent grid: 4 blocks/CU x 256 CUs (co-resident)
#define NT     16    // h rows per tile
#define SPLITS 32    // k-splits
#define KC     128   // k per split (KDIM/SPLITS)
#define TILES  4     // h-tiles per block (same k-slice -> A staged once)

typedef __attribute__((ext_vector_type(8))) short bf16x8;
typedef __attribute__((ext_vector_type(4))) float f32x4;

static __device__ __forceinline__ short f2bf(float x) {
    union { float f; unsigned u; } c; c.f = x;
    unsigned r = c.u + 0x7fff + ((c.u >> 16) & 1);   // RNE
    return (short)(r >> 16);
}

static __device__ __forceinline__ void load_lds16(const void* g, void* l) {
    __builtin_amdgcn_global_load_lds(
        (const __attribute__((address_space(1))) void*)g,
        (__attribute__((address_space(3))) void*)l, 16, 0, 0);
}

static __device__ __forceinline__ unsigned cvt_pk(float lo, float hi) {
    unsigned r;
    asm volatile("v_cvt_pk_bf16_f32 %0, %1, %2" : "=v"(r) : "v"(lo), "v"(hi));
    return r;
}

// ---------------------------------------------------------------------------
// Fused persistent kernel. R20 lesson: an ACQUIRE atomic load inside the
// spin loop emits a cache-invalidate per poll iteration -> 1024 pollers
// produce a fabric-wide invalidate storm that throttles the whole kernel
// (VALUBusy 1.9%, 7x slowdown). Fix: RELAXED poll, ONE acquire fence after
// the loop exits. Everything else identical to R20.
// Per block (bid): s = bid&31 (k-slice), ht0 = bid>>5.
//   1. glimpse: 4 (b,q) pairs (one per wave, lane = v) -> g_bf, out2
//   2. issue tile-0 W gload_lds (drains under the barrier wait)
//   3. zero out[bid*128 .. +128)
//   4. device-scope arrive; RELAXED spin; one acquire fence on exit
//   5. stage A = g_bf[0..64)[s*128..+128) once (gload_lds + XOR swizzle)
//   6. 4 tiles: {vmcnt+barrier, MFMA, stage next W, atomic tail}
// ---------------------------------------------------------------------------
__global__ __launch_bounds__(256, 4) void fused_kernel(
    const float* __restrict__ vals, const float* __restrict__ time_,
    const int* __restrict__ masks, const float* __restrict__ l_t,
    const float* __restrict__ W, const float* __restrict__ bias,
    unsigned short* __restrict__ g_bf, unsigned* __restrict__ cnt,
    float* __restrict__ out2, float* __restrict__ out)
{
    __shared__ unsigned short alds[B * KC];     // 16 KB
    __shared__ float wlds[NT * KC];             // 8 KB
    const int tid  = threadIdx.x;
    const int l    = tid & 63;
    const int w    = tid >> 6;
    const int l15  = l & 15;
    const int lk   = l >> 4;
    const int bid  = blockIdx.x;
    const int s    = bid & (SPLITS - 1);
    const int ht0  = bid >> 5;
    const int kbase = s * KC;

    // ---- 1. glimpse: pair = bid*4 + w ----
    {
        const int pair = bid * 4 + w;
        const int b = pair >> 6;
        const int q = pair & 63;
        const int v = l;

        const float* t = time_ + (size_t)b * T;
        const float tmax = t[T - 1];            // times sorted ascending

        const int   j = q & 31;
        const float sc = (q < 32) ? 1.0f : 5.0f;
        const float a = 0.5f * 0.1f * sc;       // gwidth*scale/2
        const float step = (2.0f * a) / 31.0f;
        float lin = (j == 31) ? a : (-a + step * (float)j);
        const float r = (lin + l_t[b]) * tmax;

        int lo = 0, hi = T;                     // first index with t[] > r
        while (lo < hi) {
            int mid = (lo + hi) >> 1;
            if (t[mid] > r) hi = mid; else lo = mid + 1;
        }
        const int p = lo;

        const int*   m  = masks + (size_t)b * T * V + v;
        const float* vv = vals  + (size_t)b * T * V + v;

        int i0 = -1;
        for (int i = p - 1; i >= 0; --i) {
            if (m[(size_t)i * V] != 0) { i0 = i; break; }
        }
        int i1 = -1;
        for (int i = p; i < T; ++i) {
            if (m[(size_t)i * V] != 0) { i1 = i; break; }
        }

        float y;
        if (i0 < 0 && i1 < 0) {
            y = 0.0f;
        } else if (i0 < 0) {
            y = vv[(size_t)i1 * V];
        } else if (i1 < 0) {
            y = vv[(size_t)i0 * V];
        } else {
            float t0 = t[i0], t1 = t[i1];
            float v0 = vv[(size_t)i0 * V], v1 = vv[(size_t)i1 * V];
            float den = (t1 > t0) ? (t1 - t0) : 1.0f;
            float ww = (r - t0) / den;
            ww = fminf(fmaxf(ww, 0.0f), 1.0f);
            y = v0 + ww * (v1 - v0);
        }

        const int k = v * NQ + q;
        g_bf[(size_t)b * KDIM + k] = (unsigned short)f2bf(y);
        if (k == KDIM / 2) out2[b] = y;         // g[:, 2048], fp32
    }

    // ---- 2. prefetch tile-0 W (drains under spin + A-stage) ----
    {
        const int hb = ht0 * NT;
        #pragma unroll
        for (int i = 0; i < 2; ++i) {
            const int m = w * 2 + i;            // 0..7: rows 2m, 2m+1
            const int r = 2 * m + (l >> 5);
            const int c = (l & 31) ^ (r & 7);   // 16B fp32 chunk, inv-swizzled
            load_lds16(W + (size_t)(hb + r) * FAN + kbase + c * 4,
                       wlds + m * 256);         // 256 floats per m-chunk
        }
    }

    // ---- 3. zero this block's out slice (tails atomicAdd after barrier) ----
    if (tid < 128) out[(size_t)bid * 128 + tid] = 0.0f;

    // ---- 4. device-scope arrive + RELAXED spin (one acquire on exit) ----
    __syncthreads();
    if (tid == 0) {
        __threadfence();                        // release our g_bf/out writes
        atomicAdd(cnt, 1u);
        unsigned seen;
        do {
            __builtin_amdgcn_s_sleep(16);       // back off BEFORE each poll
            seen = __hip_atomic_load(cnt, __ATOMIC_RELAXED,
                                     __HIP_MEMORY_SCOPE_AGENT);
        } while (seen < NBLK);
        __threadfence();                        // acquire ordering, ONCE
    }
    __syncthreads();

    // ---- 5. stage A once: g_bf[0..64)[kbase..+128) (shared by 4 tiles) ----
    #pragma unroll
    for (int i = 0; i < 4; ++i) {
        const int m = w * 4 + i;                // 0..15: rows 4m..4m+3
        const int r = 4 * m + (l >> 4);
        const int c = (l & 15) ^ (r & 7);       // 16B bf16 chunk, inv-swizzled
        load_lds16(g_bf + (size_t)r * KDIM + kbase + c * 8,
                   alds + m * 512);             // 512 shorts per m-chunk
    }

    // ---- 6. tiles ----
    const int ra = w * 16 + l15;                // A row (b)
    const int rb = l15;                         // W row (h offset)

    #pragma unroll
    for (int j = 0; j < TILES; ++j) {
        const int hb = (ht0 + 32 * j) * NT;

        asm volatile("s_waitcnt vmcnt(0)" ::: "memory");
        __syncthreads();

        f32x4 acc = (f32x4){0.f, 0.f, 0.f, 0.f};
        #pragma unroll
        for (int ks = 0; ks < KC / 32; ++ks) {
            const int ca = ks * 4 + lk;         // A 16B-chunk index
            const bf16x8 afrag =
                *(const bf16x8*)(alds + ra * KC + ((ca ^ (ra & 7)) << 3));

            const int cb = ks * 8 + lk * 2;     // W 16B-chunk (4 fp32) index
            const float4 f0 = *(const float4*)(wlds + rb * KC + (((cb    ) ^ (rb & 7)) << 2));
            const float4 f1 = *(const float4*)(wlds + rb * KC + (((cb + 1) ^ (rb & 7)) << 2));
            union { unsigned u[4]; bf16x8 v; } bb;
            bb.u[0] = cvt_pk(f0.x, f0.y);
            bb.u[1] = cvt_pk(f0.z, f0.w);
            bb.u[2] = cvt_pk(f1.x, f1.y);
            bb.u[3] = cvt_pk(f1.z, f1.w);

            acc = __builtin_amdgcn_mfma_f32_16x16x32_bf16(afrag, bb.v, acc, 0, 0, 0);
        }

        __syncthreads();                        // all waves done reading wlds

        // stage NEXT tile's W while this tile's tail atomics drain
        if (j + 1 < TILES) {
            const int hbn = (ht0 + 32 * (j + 1)) * NT;
            #pragma unroll
            for (int i = 0; i < 2; ++i) {
                const int m = w * 2 + i;
                const int r = 2 * m + (l >> 5);
                const int c = (l & 31) ^ (r & 7);
                load_lds16(W + (size_t)(hbn + r) * FAN + kbase + c * 4,
                           wlds + m * 256);
            }
        }

        // tail: C/D layout col = l15 (h), row = lk*4 + reg (b in 16-tile)
        const int h = hb + l15;
        #pragma unroll
        for (int rr = 0; rr < 4; ++rr) {
            const int b = w * 16 + lk * 4 + rr;
            float v = acc[rr];
            if (s == 0)
                v += bias[h] + l_t[b] * W[(size_t)h * FAN + KDIM];
            atomicAdd(&out[(size_t)b * NHID + h], v);
        }
    }
}

extern "C" void kernel_launch(void* const* d_in, const int* in_sizes, int n_in,
                              void* d_out, int out_size, void* d_ws, size_t ws_size,
                              hipStream_t stream) {
    const float* vals  = (const float*)d_in[0];
    const float* time_ = (const float*)d_in[1];
    const int*   masks = (const int*)d_in[2];
    // d_in[3] = lengths (all == T, unused)
    const float* l_t   = (const float*)d_in[4];
    const float* W     = (const float*)d_in[5];
    const float* bias  = (const float*)d_in[6];

    float* out  = (float*)d_out;                 // grep [B, NHID]
    float* out2 = out + (size_t)B * NHID;        // g[:, 2048]  [B]
    unsigned short* g_bf = (unsigned short*)d_ws;           // 512 KB
    unsigned* cnt = (unsigned*)((char*)d_ws + (1 << 20));   // arrival counter

    hipMemsetAsync(cnt, 0, sizeof(unsigned), stream);       // re-zero each call

    fused_kernel<<<NBLK, 256, 0, stream>>>(vals, time_, masks, l_t, W, bias,
                                           g_bf, cnt, out2, out);
}

// Round 22
// 34.354 us; speedup vs baseline: 6.1432x; 4.8631x over previous
//
#include <hip/hip_runtime.h>
#include <hip/hip_bf16.h>

#define B    64
#define T    4096
#define V    64
#define NQ   64      // NGRAN * NGLIMPSE
#define NHID 2048
#define KDIM 4096    // V * NQ
#define FAN  4097    // KDIM + 1 (l_t column)

#define NT     16    // h rows per gemm block
#define SPLITS 32    // K-split across gemm blocks (R16 had 16)
#define KC     128   // k per block (KDIM/SPLITS); LDS 24KB -> 6 blocks/CU

typedef __attribute__((ext_vector_type(8))) short bf16x8;
typedef __attribute__((ext_vector_type(4))) float f32x4;

static __device__ __forceinline__ short f2bf(float x) {
    union { float f; unsigned u; } c; c.f = x;
    unsigned r = c.u + 0x7fff + ((c.u >> 16) & 1);   // RNE
    return (short)(r >> 16);
}

static __device__ __forceinline__ void load_lds16(const void* g, void* l) {
    __builtin_amdgcn_global_load_lds(
        (const __attribute__((address_space(1))) void*)g,
        (__attribute__((address_space(3))) void*)l, 16, 0, 0);
}

static __device__ __forceinline__ unsigned cvt_pk(float lo, float hi) {
    unsigned r;
    asm volatile("v_cvt_pk_bf16_f32 %0, %1, %2" : "=v"(r) : "v"(lo), "v"(hi));
    return r;
}

// ---------------------------------------------------------------------------
// Kernel 1: glimpse interpolation (~6.5 us measured). grid = (B, NQ),
// block = 64 (lane = v). Writes g_bf16[b][k] (k=v*NQ+q), out2, and zeroes
// the out[] slice for the gemm's atomicAdd (stream-ordered before gemm).
// ---------------------------------------------------------------------------
__global__ __launch_bounds__(64) void glimpse_kernel(
    const float* __restrict__ vals, const float* __restrict__ time_,
    const int* __restrict__ masks, const float* __restrict__ l_t,
    unsigned short* __restrict__ g_bf, float* __restrict__ out2,
    float* __restrict__ out)
{
    const int b = blockIdx.x;
    const int q = blockIdx.y;
    const int v = threadIdx.x;

    if (v < 32) out[(size_t)b * NHID + q * 32 + v] = 0.0f;

    const float* t = time_ + (size_t)b * T;
    const float tmax = t[T - 1];          // times sorted ascending

    const int   j = q & 31;
    const float s = (q < 32) ? 1.0f : 5.0f;
    const float a = 0.5f * 0.1f * s;      // gwidth*s/2
    const float step = (2.0f * a) / 31.0f;
    float lin = (j == 31) ? a : (-a + step * (float)j);
    const float r = (lin + l_t[b]) * tmax;

    // binary search: p = first index with t[p] > r  (wave-uniform)
    int lo = 0, hi = T;
    while (lo < hi) {
        int mid = (lo + hi) >> 1;
        if (t[mid] > r) hi = mid; else lo = mid + 1;
    }
    const int p = lo;

    const int*   m  = masks + (size_t)b * T * V + v;
    const float* vv = vals  + (size_t)b * T * V + v;

    int i0 = -1;
    for (int i = p - 1; i >= 0; --i) {
        if (m[(size_t)i * V] != 0) { i0 = i; break; }
    }
    int i1 = -1;
    for (int i = p; i < T; ++i) {
        if (m[(size_t)i * V] != 0) { i1 = i; break; }
    }

    float y;
    if (i0 < 0 && i1 < 0) {
        y = 0.0f;
    } else if (i0 < 0) {
        y = vv[(size_t)i1 * V];
    } else if (i1 < 0) {
        y = vv[(size_t)i0 * V];
    } else {
        float t0 = t[i0], t1 = t[i1];
        float v0 = vv[(size_t)i0 * V], v1 = vv[(size_t)i1 * V];
        float den = (t1 > t0) ? (t1 - t0) : 1.0f;
        float w = (r - t0) / den;
        w = fminf(fmaxf(w, 0.0f), 1.0f);
        y = v0 + w * (v1 - v0);
    }

    const int k = v * NQ + q;
    g_bf[(size_t)b * KDIM + k] = (unsigned short)f2bf(y);
    if (k == KDIM / 2) out2[b] = y;             // g[:, 2048], fp32
}

// ---------------------------------------------------------------------------
// Kernel 2: MFMA GEMM, gload_lds staging + both-sides XOR swizzle (R16
// structure), k-slice halved: SPLITS=32, KC=128 -> 4096 blocks, 24KB LDS,
// 6 blocks/CU resident (was 3) to double in-flight cold W loads per CU.
// Staging/read swizzle geometry identical to the R19/R20-validated kernel.
// grid = (NHID/NT, SPLITS) = (128, 32) x 256 thr (4 waves).
// Wave w: m-rows [16w,16w+16) x 16 h x 128 k = 4 MFMAs. atomicAdd tail
// (out pre-zeroed by glimpse).
// ---------------------------------------------------------------------------
__global__ __launch_bounds__(256) void gemm_mfma(
    const unsigned short* __restrict__ g_bf, const float* __restrict__ l_t,
    const float* __restrict__ W, const float* __restrict__ bias,
    float* __restrict__ out)
{
    __shared__ unsigned short alds[B * KC];     // 16 KB
    __shared__ float wlds[NT * KC];             // 8 KB
    const int tid  = threadIdx.x;
    const int l    = tid & 63;
    const int w    = tid >> 6;
    const int l15  = l & 15;
    const int lk   = l >> 4;                    // k-group 0..3
    const int hbase = blockIdx.x * NT;
    const int s     = blockIdx.y;
    const int kbase = s * KC;

    // ---- stage A: 16 wave-chunks of 1KB; chunk m covers rows 4m..4m+3.
    // lane l -> LDS linear; source chunk inverse-swizzled: row r's chunk c
    // lands at position c^(r&7) (16 chunks of 8 bf16 per row).
    #pragma unroll
    for (int i = 0; i < 4; ++i) {
        const int m = w * 4 + i;                // 0..15
        const int r = 4 * m + (l >> 4);
        const int c = (l & 15) ^ (r & 7);
        load_lds16(g_bf + (size_t)r * KDIM + kbase + c * 8,
                   alds + m * 512);             // 512 shorts per chunk
    }
    // ---- stage W: 8 wave-chunks of 1KB; chunk m covers rows 2m, 2m+1
    // (32 chunks of 4 fp32 per row), same inverse swizzle.
    #pragma unroll
    for (int i = 0; i < 2; ++i) {
        const int m = w * 2 + i;                // 0..7
        const int r = 2 * m + (l >> 5);
        const int c = (l & 31) ^ (r & 7);
        load_lds16(W + (size_t)(hbase + r) * FAN + kbase + c * 4,
                   wlds + m * 256);             // 256 floats per chunk
    }
    asm volatile("s_waitcnt vmcnt(0)" ::: "memory");
    __syncthreads();

    f32x4 acc = (f32x4){0.f, 0.f, 0.f, 0.f};
    const int ra = w * 16 + l15;                // A row (b)
    const int rb = l15;                         // W row (h offset)

    #pragma unroll
    for (int ks = 0; ks < KC / 32; ++ks) {      // 4 MFMAs
        const int ca = ks * 4 + lk;             // A 16B-chunk index
        const bf16x8 afrag =
            *(const bf16x8*)(alds + ra * KC + ((ca ^ (ra & 7)) << 3));

        const int cb = ks * 8 + lk * 2;         // W 16B-chunk (4 fp32) index
        const float4 f0 = *(const float4*)(wlds + rb * KC + (((cb    ) ^ (rb & 7)) << 2));
        const float4 f1 = *(const float4*)(wlds + rb * KC + (((cb + 1) ^ (rb & 7)) << 2));
        union { unsigned u[4]; bf16x8 v; } bb;
        bb.u[0] = cvt_pk(f0.x, f0.y);
        bb.u[1] = cvt_pk(f0.z, f0.w);
        bb.u[2] = cvt_pk(f1.x, f1.y);
        bb.u[3] = cvt_pk(f1.z, f1.w);

        acc = __builtin_amdgcn_mfma_f32_16x16x32_bf16(afrag, bb.v, acc, 0, 0, 0);
    }

    // C/D layout: col = lane&15 (h offset), row = (lane>>4)*4 + reg (b offset)
    const int h = hbase + l15;
    #pragma unroll
    for (int rr = 0; rr < 4; ++rr) {
        const int b = w * 16 + lk * 4 + rr;
        float v = acc[rr];
        if (s == 0)
            v += bias[h] + l_t[b] * W[(size_t)h * FAN + KDIM];
        atomicAdd(&out[(size_t)b * NHID + h], v);
    }
}

extern "C" void kernel_launch(void* const* d_in, const int* in_sizes, int n_in,
                              void* d_out, int out_size, void* d_ws, size_t ws_size,
                              hipStream_t stream) {
    const float* vals  = (const float*)d_in[0];
    const float* time_ = (const float*)d_in[1];
    const int*   masks = (const int*)d_in[2];
    // d_in[3] = lengths (all == T, unused)
    const float* l_t   = (const float*)d_in[4];
    const float* W     = (const float*)d_in[5];
    const float* bias  = (const float*)d_in[6];

    float* out  = (float*)d_out;                 // grep [B, NHID]
    float* out2 = out + (size_t)B * NHID;        // g[:, 2048]  [B]
    unsigned short* g_bf = (unsigned short*)d_ws; // bf16 [B][KDIM] = 512 KB

    dim3 g1(B, NQ);
    glimpse_kernel<<<g1, 64, 0, stream>>>(vals, time_, masks, l_t, g_bf, out2, out);

    dim3 g2(NHID / NT, SPLITS);
    gemm_mfma<<<g2, 256, 0, stream>>>(g_bf, l_t, W, bias, out);
}

// Round 23
// 29.493 us; speedup vs baseline: 7.1556x; 1.1648x over previous
//
#include <hip/hip_runtime.h>
#include <hip/hip_bf16.h>

#define B    64
#define T    4096
#define V    64
#define NQ   64      // NGRAN * NGLIMPSE
#define NHID 2048
#define KDIM 4096    // V * NQ
#define FAN  4097    // KDIM + 1 (l_t column)

#define NT     16    // h rows per gemm block
#define SPLITS 16    // K-split across gemm blocks
#define KC     256   // k per block (KDIM/SPLITS)

typedef __attribute__((ext_vector_type(8))) short bf16x8;
typedef __attribute__((ext_vector_type(4))) float f32x4;

static __device__ __forceinline__ short f2bf(float x) {
    union { float f; unsigned u; } c; c.f = x;
    unsigned r = c.u + 0x7fff + ((c.u >> 16) & 1);   // RNE
    return (short)(r >> 16);
}

static __device__ __forceinline__ void load_lds16(const void* g, void* l) {
    __builtin_amdgcn_global_load_lds(
        (const __attribute__((address_space(1))) void*)g,
        (__attribute__((address_space(3))) void*)l, 16, 0, 0);
}

static __device__ __forceinline__ unsigned cvt_pk(float lo, float hi) {
    unsigned r;
    asm volatile("v_cvt_pk_bf16_f32 %0, %1, %2" : "=v"(r) : "v"(lo), "v"(hi));
    return r;
}

// ---------------------------------------------------------------------------
// Kernel 1: glimpse interpolation (~6.5 us measured). grid = (B, NQ),
// block = 64 (lane = v). Writes g_bf16[b][k] (k=v*NQ+q), out2, and zeroes
// the out[] slice for the gemm's atomicAdd (stream-ordered before gemm).
// ---------------------------------------------------------------------------
__global__ __launch_bounds__(64) void glimpse_kernel(
    const float* __restrict__ vals, const float* __restrict__ time_,
    const int* __restrict__ masks, const float* __restrict__ l_t,
    unsigned short* __restrict__ g_bf, float* __restrict__ out2,
    float* __restrict__ out)
{
    const int b = blockIdx.x;
    const int q = blockIdx.y;
    const int v = threadIdx.x;

    if (v < 32) out[(size_t)b * NHID + q * 32 + v] = 0.0f;

    const float* t = time_ + (size_t)b * T;
    const float tmax = t[T - 1];          // times sorted ascending

    const int   j = q & 31;
    const float s = (q < 32) ? 1.0f : 5.0f;
    const float a = 0.5f * 0.1f * s;      // gwidth*s/2
    const float step = (2.0f * a) / 31.0f;
    float lin = (j == 31) ? a : (-a + step * (float)j);
    const float r = (lin + l_t[b]) * tmax;

    // binary search: p = first index with t[p] > r  (wave-uniform)
    int lo = 0, hi = T;
    while (lo < hi) {
        int mid = (lo + hi) >> 1;
        if (t[mid] > r) hi = mid; else lo = mid + 1;
    }
    const int p = lo;

    const int*   m  = masks + (size_t)b * T * V + v;
    const float* vv = vals  + (size_t)b * T * V + v;

    int i0 = -1;
    for (int i = p - 1; i >= 0; --i) {
        if (m[(size_t)i * V] != 0) { i0 = i; break; }
    }
    int i1 = -1;
    for (int i = p; i < T; ++i) {
        if (m[(size_t)i * V] != 0) { i1 = i; break; }
    }

    float y;
    if (i0 < 0 && i1 < 0) {
        y = 0.0f;
    } else if (i0 < 0) {
        y = vv[(size_t)i1 * V];
    } else if (i1 < 0) {
        y = vv[(size_t)i0 * V];
    } else {
        float t0 = t[i0], t1 = t[i1];
        float v0 = vv[(size_t)i0 * V], v1 = vv[(size_t)i1 * V];
        float den = (t1 > t0) ? (t1 - t0) : 1.0f;
        float w = (r - t0) / den;
        w = fminf(fmaxf(w, 0.0f), 1.0f);
        y = v0 + w * (v1 - v0);
    }

    const int k = v * NQ + q;
    g_bf[(size_t)b * KDIM + k] = (unsigned short)f2bf(y);
    if (k == KDIM / 2) out2[b] = y;             // g[:, 2048], fp32
}

// ---------------------------------------------------------------------------
// Kernel 2: MFMA GEMM — R16 champion (30.0 us) restored verbatim except the
// staging ORDER: W (cold L3 stream) issued FIRST, A (XCD-L2-resident after
// first block) second, so W's long-latency fills overlap A's short ones
// before the single vmcnt(0). gload_lds + both-sides XOR swizzle.
// grid = (NHID/NT, SPLITS) = (128,16) = 2048 blocks x 256 thr (4 waves).
// Wave w: m-rows [16w,16w+16) x 16 h x 256 k = 8 MFMAs. atomicAdd tail
// (out pre-zeroed by glimpse).
// ---------------------------------------------------------------------------
__global__ __launch_bounds__(256) void gemm_mfma(
    const unsigned short* __restrict__ g_bf, const float* __restrict__ l_t,
    const float* __restrict__ W, const float* __restrict__ bias,
    float* __restrict__ out)
{
    __shared__ unsigned short alds[B * KC];     // 32 KB
    __shared__ float wlds[NT * KC];             // 16 KB
    const int tid  = threadIdx.x;
    const int l    = tid & 63;
    const int w    = tid >> 6;
    const int l15  = l & 15;
    const int lk   = l >> 4;                    // k-group 0..3
    const int hbase = blockIdx.x * NT;
    const int s     = blockIdx.y;
    const int kbase = s * KC;

    // ---- stage W FIRST (cold stream): 16 x 1KB wave-chunks; chunk = one
    // fp32 row of 64 x 16B, inverse-swizzled source, linear LDS dest.
    #pragma unroll
    for (int i = 0; i < 4; ++i) {
        const int r = w * 4 + i;
        const int c = l ^ (r & 7);              // 16B = 4 float chunk
        load_lds16(W + (size_t)(hbase + r) * FAN + kbase + c * 4,
                   wlds + r * KC);
    }
    // ---- stage A second: 32 x 1KB wave-chunks; chunk m covers rows 2m,2m+1.
    #pragma unroll
    for (int i = 0; i < 8; ++i) {
        const int m = w * 8 + i;
        const int r = 2 * m + (l >> 5);
        const int c = (l & 31) ^ (r & 7);       // 16B = 8 bf16 chunk
        load_lds16(g_bf + (size_t)r * KDIM + kbase + c * 8,
                   alds + m * 512);
    }
    asm volatile("s_waitcnt vmcnt(0)" ::: "memory");
    __syncthreads();

    f32x4 acc = (f32x4){0.f, 0.f, 0.f, 0.f};
    const int ra = w * 16 + l15;                // A row (b)
    const int rb = l15;                         // W row (h offset)

    #pragma unroll
    for (int ks = 0; ks < 8; ++ks) {
        // A fragment: source chunk ca at swizzled position ca^(ra&7)
        const int ca = ks * 4 + lk;
        const bf16x8 afrag =
            *(const bf16x8*)(alds + ra * KC + ((ca ^ (ra & 7)) << 3));

        // B fragment: 8 floats = chunks cb, cb+1 (cb even), swizzled; cvt_pk
        const int cb = ks * 8 + lk * 2;
        const float4 f0 = *(const float4*)(wlds + rb * KC + (((cb    ) ^ (rb & 7)) << 2));
        const float4 f1 = *(const float4*)(wlds + rb * KC + (((cb + 1) ^ (rb & 7)) << 2));
        union { unsigned u[4]; bf16x8 v; } bb;
        bb.u[0] = cvt_pk(f0.x, f0.y);
        bb.u[1] = cvt_pk(f0.z, f0.w);
        bb.u[2] = cvt_pk(f1.x, f1.y);
        bb.u[3] = cvt_pk(f1.z, f1.w);

        acc = __builtin_amdgcn_mfma_f32_16x16x32_bf16(afrag, bb.v, acc, 0, 0, 0);
    }

    // C/D layout: col = lane&15 (h offset), row = (lane>>4)*4 + reg (b offset)
    const int h = hbase + l15;
    #pragma unroll
    for (int rr = 0; rr < 4; ++rr) {
        const int b = w * 16 + lk * 4 + rr;
        float v = acc[rr];
        if (s == 0)
            v += bias[h] + l_t[b] * W[(size_t)h * FAN + KDIM];
        atomicAdd(&out[(size_t)b * NHID + h], v);
    }
}

extern "C" void kernel_launch(void* const* d_in, const int* in_sizes, int n_in,
                              void* d_out, int out_size, void* d_ws, size_t ws_size,
                              hipStream_t stream) {
    const float* vals  = (const float*)d_in[0];
    const float* time_ = (const float*)d_in[1];
    const int*   masks = (const int*)d_in[2];
    // d_in[3] = lengths (all == T, unused)
    const float* l_t   = (const float*)d_in[4];
    const float* W     = (const float*)d_in[5];
    const float* bias  = (const float*)d_in[6];

    float* out  = (float*)d_out;                 // grep [B, NHID]
    float* out2 = out + (size_t)B * NHID;        // g[:, 2048]  [B]
    unsigned short* g_bf = (unsigned short*)d_ws; // bf16 [B][KDIM] = 512 KB

    dim3 g1(B, NQ);
    glimpse_kernel<<<g1, 64, 0, stream>>>(vals, time_, masks, l_t, g_bf, out2, out);

    dim3 g2(NHID / NT, SPLITS);
    gemm_mfma<<<g2, 256, 0, stream>>>(g_bf, l_t, W, bias, out);
}